// Round 7
// baseline (1363.119 us; speedup 1.0000x reference)
//
#include <hip/hip_runtime.h>
#include <math.h>

// LDGCNN forward: 4 EdgeConv blocks (knn K=20) + 1x1 conv block + global max pool + 3 FC.
// B=8, N=2048. Feature buffer X: (B, N, XS) rows, columns [pts(3)|f1(64)|f2(64)|f3(64)|f4(128)].
// XS=324 keeps rows 16B-aligned for float4 loads (column 323 is an unused pad).
//
// R17: EdgeConv is linear in (nbr, ctr): h[n,k,o] = H[idx[n,k],o] + G[n,o] with H = X.Wa^T,
// G = X.Wd^T -> dense GEMM (k_hg) + cache-resident gather+max (k_edgemax).
// R19: k_stage5 RB 8->32 (W5T L2 traffic 1/RB). 216 -> 168us.
// R20 (this round): k_stage5 LDS:FMA 1:16 -> 1:32. R19 was LDS-pipe bound: 16 ds_read_b128
// per 256 FMAs = 3072 cyc/CU LDS vs 2048 cyc/SIMD VALU per c4 iter. Now each thread owns
// 2 output slots (8 outputs) x 8 rows: 8 reads per 256 FMAs -> LDS 1536 < VALU 2048.

constexpr int BB = 8;
constexpr int NN = 2048;
constexpr int KK = 20;
constexpr int CT = 323;
constexpr int XS = 324;
constexpr int X4S = XS / 4;   // 81 float4 per row
constexpr float NEGS = 0.2f;

__device__ __forceinline__ float lrelu(float v) { return v > 0.0f ? v : NEGS * v; }

__device__ __forceinline__ void atomicMaxF(float* addr, float v) {
    if (v >= 0.0f) atomicMax((int*)addr, __float_as_int(v));
    else           atomicMin((unsigned int*)addr, __float_as_uint(v));
}

__device__ __forceinline__ void fma4(float4& a, float x, const float4 w) {
    a.x = fmaf(x, w.x, a.x); a.y = fmaf(x, w.y, a.y);
    a.z = fmaf(x, w.z, a.z); a.w = fmaf(x, w.w, a.w);
}

// ---- fused prep: WT packs + W5T transpose + gfeat init + transpose/sq0 + X zero-fill -----
// WT layout per stage: [4*KC4 channel rows][2*COUT floats]: cols [0,COUT)=Wa[o][c],
// [COUT,2COUT)=Wd[o][c]=W[o][C+c]-W[o][c]. Channel rows c>=C zero-padded (X cols beyond the
// written prefix are zero-filled, so pad contributions are exactly 0).
// float4 bases: st1@0 (4x32), st2@128 (68x32), st3@2304 (132x32), st4@6528 (196x64).
constexpr int WTOT = 19072;
__global__ void k_prep_all(const float* __restrict__ W1, const float* __restrict__ W2,
                           const float* __restrict__ W3, const float* __restrict__ W4,
                           const float* __restrict__ W5, const float* __restrict__ x,
                           float4* __restrict__ WT4, float* __restrict__ W5T,
                           float* __restrict__ gfeat, float* __restrict__ X,
                           float* __restrict__ sq) {
    int j = blockIdx.x * blockDim.x + threadIdx.x;
    if (j < WTOT) {
        int base, Cout, C;
        const float* W;
        if (j < 128)       { base = 0;    Cout = 64;  C = 3;   W = W1; }
        else if (j < 2304) { base = 128;  Cout = 64;  C = 67;  W = W2; }
        else if (j < 6528) { base = 2304; Cout = 64;  C = 131; W = W3; }
        else               { base = 6528; Cout = 128; C = 195; W = W4; }
        int W4w = Cout / 2;                 // 2*Cout/4 float4 groups per channel row
        int local = j - base;
        int c = local / W4w, og = local - c * W4w;
        float v[4];
#pragma unroll
        for (int q = 0; q < 4; ++q) {
            int o2 = 4 * og + q;
            if (c >= C) v[q] = 0.f;
            else if (o2 < Cout) v[q] = W[(size_t)o2 * 2 * C + c];
            else {
                int o = o2 - Cout;
                v[q] = W[(size_t)o * 2 * C + C + c] - W[(size_t)o * 2 * C + c];
            }
        }
        WT4[j] = make_float4(v[0], v[1], v[2], v[3]);
    } else if (j < WTOT + XS * 1024) {
        int t = j - WTOT;
        int c = t / 1024, o = t % 1024;
        W5T[t] = (c < CT) ? W5[(size_t)o * CT + c] : 0.f;   // row 323 zeroed
    } else if (j < WTOT + XS * 1024 + BB * 1024) {
        gfeat[j - WTOT - XS * 1024] = -INFINITY;
    } else if (j < WTOT + XS * 1024 + BB * 1024 + BB * NN) {
        int i = j - WTOT - XS * 1024 - BB * 1024;            // b*NN + n
        int b = i >> 11, n = i & 2047;
        const float* xb = x + (size_t)b * 3 * NN;
        float vx = xb[n], vy = xb[NN + n], vz = xb[2 * NN + n];
        float* row = X + (size_t)i * XS;
        row[0] = vx; row[1] = vy; row[2] = vz; row[3] = 0.f;
        sq[i] = vx * vx + vy * vy + vz * vz;
    } else if (j < WTOT + XS * 1024 + BB * 1024 + BB * NN + BB * NN * 80) {
        // zero-fill X feature columns (float4 indices 1..80 of each row; col 3 done above)
        int t = j - (WTOT + XS * 1024 + BB * 1024 + BB * NN);
        int row = t / 80, c4 = 1 + (t - 80 * row);
        ((float4*)X)[(size_t)row * X4S + c4] = make_float4(0.f, 0.f, 0.f, 0.f);
    }
}

// ---- dist[b][n][m] = max(sq_n + sq_m - 2*dot, 0) — SYMMETRIC: only tiles ti>=tj ----------
// 128x128 tile, 8x8 per thread. Off-diagonal blocks write direct + mirrored (LDS transpose).
constexpr int TM = 128;
__global__ __launch_bounds__(256) void k_dist(const float* __restrict__ X,
                                              const float* __restrict__ sq,
                                              float* __restrict__ dist, int C) {
    int b = blockIdx.z;
    int blk = blockIdx.x;                 // 0..135 -> (ti, tj), ti >= tj
    int ti = (int)((sqrtf(8.0f * blk + 1.0f) - 1.0f) * 0.5f);
    while ((ti + 1) * (ti + 2) / 2 <= blk) ++ti;
    while (ti * (ti + 1) / 2 > blk) --ti;
    int tj = blk - ti * (ti + 1) / 2;
    int m0 = ti * TM;                     // col tile
    int n0 = tj * TM;                     // row tile
    __shared__ float smem[4352];          // 17 KB: staging (16 KB) / transpose T[32][129]
    float* AsB = smem;                    // As[16][TM]
    float* BsB = smem + 2048;             // Bs[16][TM]
    int tid = threadIdx.x;
    int tx = tid & 15;        // cols: m0 + tx + 16*j
    int ty = tid >> 4;        // rows: n0 + ty*8 + i
    float acc[8][8] = {};
    const float* Xb = X + (size_t)b * NN * XS;
    int sr = tid & 127;       // staging row
    int sc0 = (tid >> 7) * 8; // staging channel half (0 or 8)
    for (int c0 = 0; c0 < C; c0 += 16) {
        const float* arow = Xb + (size_t)(n0 + sr) * XS + c0 + sc0;
        const float* brow = Xb + (size_t)(m0 + sr) * XS + c0 + sc0;
        float4 a0 = *(const float4*)(arow);
        float4 a1 = *(const float4*)(arow + 4);
        float4 b0 = *(const float4*)(brow);
        float4 b1 = *(const float4*)(brow + 4);
        float av[8] = {a0.x, a0.y, a0.z, a0.w, a1.x, a1.y, a1.z, a1.w};
        float bv8[8] = {b0.x, b0.y, b0.z, b0.w, b1.x, b1.y, b1.z, b1.w};
#pragma unroll
        for (int i = 0; i < 8; ++i) {
            bool inr = (c0 + sc0 + i) < C;
            AsB[(sc0 + i) * TM + sr] = inr ? av[i] : 0.f;
            BsB[(sc0 + i) * TM + sr] = inr ? bv8[i] : 0.f;
        }
        __syncthreads();
#pragma unroll
        for (int cc = 0; cc < 16; ++cc) {
            float4 a0r = *(const float4*)&AsB[cc * TM + ty * 8];
            float4 a1r = *(const float4*)&AsB[cc * TM + ty * 8 + 4];
            float a[8] = {a0r.x, a0r.y, a0r.z, a0r.w, a1r.x, a1r.y, a1r.z, a1r.w};
            float bv[8];
#pragma unroll
            for (int j = 0; j < 8; ++j) bv[j] = BsB[cc * TM + tx + 16 * j];
#pragma unroll
            for (int i = 0; i < 8; ++i)
#pragma unroll
                for (int j = 0; j < 8; ++j)
                    acc[i][j] = fmaf(a[i], bv[j], acc[i][j]);
        }
        __syncthreads();
    }
    const float* sqb = sq + b * NN;
    float* db = dist + (size_t)b * NN * NN;
    float sm[8];
#pragma unroll
    for (int j = 0; j < 8; ++j) sm[j] = sqb[m0 + tx + 16 * j];
#pragma unroll
    for (int i = 0; i < 8; ++i) {
        int n = n0 + ty * 8 + i;
        float sn = sqb[n];
#pragma unroll
        for (int j = 0; j < 8; ++j) {
            float d = fmaxf(sn + sm[j] - 2.f * acc[i][j], 0.f);
            acc[i][j] = d;                                   // keep for mirror
            db[(size_t)n * NN + m0 + tx + 16 * j] = d;
        }
    }
    if (ti != tj) {
        // mirrored tile: rows m0.., cols n0.. — 4 passes of 32 m-rows via LDS transpose
        float* T = smem;                  // [32][129]
        int r = tid >> 3;                 // 0..31
        int c0 = (tid & 7) * 16;          // 0..112
#pragma unroll
        for (int p = 0; p < 4; ++p) {
            __syncthreads();              // protect staging/previous pass reads
#pragma unroll
            for (int jj = 0; jj < 2; ++jj) {
                int j = 2 * p + jj;       // m_local = 32p + tx + 16jj
#pragma unroll
                for (int i = 0; i < 8; ++i)
                    T[(tx + 16 * jj) * 129 + ty * 8 + i] = acc[i][j];
            }
            __syncthreads();
            float v[16];
#pragma unroll
            for (int k = 0; k < 16; ++k) v[k] = T[r * 129 + c0 + k];
            float* dst = db + (size_t)(m0 + 32 * p + r) * NN + n0 + c0;
#pragma unroll
            for (int k = 0; k < 4; ++k)
                *(float4*)(dst + 4 * k) = make_float4(v[4 * k], v[4 * k + 1],
                                                      v[4 * k + 2], v[4 * k + 3]);
        }
    }
}

// ---- Batcher odd-even mergesort network, N=16, fully unrolled (registers) ----------------
__device__ __forceinline__ void sortnet16(unsigned long long* k) {
#pragma unroll
    for (int p = 1; p < 16; p <<= 1) {
#pragma unroll
        for (int q = p; q >= 1; q >>= 1) {
#pragma unroll
            for (int j = q % p; j + q < 16; j += 2 * q) {
#pragma unroll
                for (int i = 0; i < q; ++i) {
                    int a = j + i, bx = j + i + q;
                    if (bx < 16 && (a / (2 * p)) == (bx / (2 * p))) {
                        unsigned long long ka = k[a], kb = k[bx];
                        bool sw = kb < ka;
                        k[a]  = sw ? kb : ka;
                        k[bx] = sw ? ka : kb;
                    }
                }
            }
        }
    }
}

// ---- top-K smallest per row: key = (bits(d)<<11)|m; ties -> lower m (lax.top_k) ----------
__global__ __launch_bounds__(128) void k_select(const float* __restrict__ dist,
                                                int* __restrict__ idx) {
    int bn = blockIdx.x;   // b*NN + n
    int tid = threadIdx.x;
    int wv = tid >> 6;
    int lane = tid & 63;
    const float* drow = dist + (size_t)bn * NN;
    int m0 = wv * 1024 + lane * 16;
    unsigned long long k[16];
#pragma unroll
    for (int i = 0; i < 4; ++i) {
        float4 v = *(const float4*)(drow + m0 + 4 * i);
        k[4 * i + 0] = ((unsigned long long)__float_as_uint(v.x) << 11) | (unsigned)(m0 + 4 * i + 0);
        k[4 * i + 1] = ((unsigned long long)__float_as_uint(v.y) << 11) | (unsigned)(m0 + 4 * i + 1);
        k[4 * i + 2] = ((unsigned long long)__float_as_uint(v.z) << 11) | (unsigned)(m0 + 4 * i + 2);
        k[4 * i + 3] = ((unsigned long long)__float_as_uint(v.w) << 11) | (unsigned)(m0 + 4 * i + 3);
    }
    sortnet16(k);
    __shared__ unsigned long long wl[2 * KK];
    for (int kk = 0; kk < KK; ++kk) {
        unsigned long long g = k[0];
#pragma unroll
        for (int s = 1; s < 64; s <<= 1) {
            unsigned long long o = (unsigned long long)__shfl_xor((long long)g, s, 64);
            if (o < g) g = o;
        }
        bool win = (k[0] == g);
#pragma unroll
        for (int i = 0; i < 15; ++i) k[i] = win ? k[i + 1] : k[i];
        k[15] = win ? ~0ull : k[15];
        if (lane == 0) wl[wv * KK + kk] = g;
    }
    __syncthreads();
    if (wv == 0) {
        unsigned long long mk = (lane < 2 * KK) ? wl[lane] : ~0ull;
        int* orow = idx + (size_t)bn * KK;
        for (int kk = 0; kk < KK; ++kk) {
            unsigned long long g = mk;
#pragma unroll
            for (int s = 1; s < 64; s <<= 1) {
                unsigned long long o = (unsigned long long)__shfl_xor((long long)g, s, 64);
                if (o < g) g = o;
            }
            if (mk == g) mk = ~0ull;
            if (lane == 0) orow[kk] = (int)(g & 2047u);
        }
    }
}

// ---- k_hg: H = X.Wa^T, G = X.Wd^T — dense GEMM, no gather. -------------------------------
// Block: 256 threads, RB2=32 point-rows. Thread owns 4 outputs (og) x RPT rows; X rows
// staged in LDS; weight float4 loads coalesced and L2-resident (WT <= 200KB/stage).
template <int KC4, int COUT>
__global__ __launch_bounds__(256)
void k_hg(const float* __restrict__ X, const float4* __restrict__ WT4,
          float* __restrict__ H, float* __restrict__ G) {
    constexpr int W4 = COUT / 2;            // 2*COUT/4 float4 outputs per channel row
    constexpr int RB2 = 32;
    constexpr int RPT = RB2 * W4 / 256;     // rows per thread (8 for COUT=128, 4 for 64)
    int bn0 = blockIdx.x * RB2;
    __shared__ float4 xs[RB2][KC4];
    int tid = threadIdx.x;
    const float4* X4 = (const float4*)X;
    for (int j = tid; j < RB2 * KC4; j += 256) {
        int r = j / KC4, c = j - r * KC4;
        xs[r][c] = X4[(size_t)(bn0 + r) * X4S + c];
    }
    __syncthreads();
    int og = tid & (W4 - 1);
    int rg = tid / W4;                      // row group
    float4 acc[RPT];
#pragma unroll
    for (int i = 0; i < RPT; ++i) acc[i] = make_float4(0.f, 0.f, 0.f, 0.f);
#pragma unroll 2
    for (int c4 = 0; c4 < KC4; ++c4) {
        float4 w0 = WT4[(size_t)(4 * c4 + 0) * W4 + og];
        float4 w1 = WT4[(size_t)(4 * c4 + 1) * W4 + og];
        float4 w2 = WT4[(size_t)(4 * c4 + 2) * W4 + og];
        float4 w3 = WT4[(size_t)(4 * c4 + 3) * W4 + og];
#pragma unroll
        for (int i = 0; i < RPT; ++i) {
            float4 xv = xs[rg * RPT + i][c4];
            fma4(acc[i], xv.x, w0);
            fma4(acc[i], xv.y, w1);
            fma4(acc[i], xv.z, w2);
            fma4(acc[i], xv.w, w3);
        }
    }
    int o2 = 4 * og;
#pragma unroll
    for (int i = 0; i < RPT; ++i) {
        int bn = bn0 + rg * RPT + i;
        if (o2 < COUT) *(float4*)&H[(size_t)bn * COUT + o2] = acc[i];
        else           *(float4*)&G[(size_t)bn * COUT + (o2 - COUT)] = acc[i];
    }
}

// ---- k_edgemax: X[bn, outoff+o] = max_k lrelu((H[idx[bn,k],o] + G[bn,o])*s+b) ------------
// One wave per point: 20 independent coalesced H-row reads (cache-resident), 3 VALU/elem.
// Epilogue fuses sq[bn] += sum(new channels^2) (full-wave shuffle reduce).
template <int COUT>
__global__ __launch_bounds__(256)
void k_edgemax(const float* __restrict__ H, const float* __restrict__ G,
               const int* __restrict__ idx, const float* __restrict__ scale,
               const float* __restrict__ bias, int outoff,
               float* __restrict__ X, float* __restrict__ sq) {
    constexpr int CPL = COUT / 64;          // cols per lane (1 or 2)
    int wv = threadIdx.x >> 6, lane = threadIdx.x & 63;
    int bn = blockIdx.x * 4 + wv;
    int b = bn >> 11;                       // NN = 2048
    int id = idx[(size_t)bn * KK + (lane < KK ? lane : 0)];
    float gv[CPL], sv[CPL], bv[CPL], mx[CPL];
#pragma unroll
    for (int q = 0; q < CPL; ++q) {
        int o = lane + 64 * q;
        gv[q] = G[(size_t)bn * COUT + o];
        sv[q] = scale[o];
        bv[q] = bias[o];
        mx[q] = -INFINITY;
    }
#pragma unroll
    for (int k = 0; k < KK; ++k) {
        int m = __shfl(id, k, 64);
        const float* hrow = H + (size_t)(b * NN + m) * COUT;
#pragma unroll
        for (int q = 0; q < CPL; ++q) {
            float v = hrow[lane + 64 * q] + gv[q];
            mx[q] = fmaxf(mx[q], lrelu(v * sv[q] + bv[q]));
        }
    }
    float* orow = X + (size_t)bn * XS + outoff;
    float v = 0.f;
#pragma unroll
    for (int q = 0; q < CPL; ++q) {
        orow[lane + 64 * q] = mx[q];
        v = fmaf(mx[q], mx[q], v);
    }
#pragma unroll
    for (int s = 1; s < 64; s <<= 1) v += __shfl_xor(v, s, 64);
    if (lane == 0) sq[bn] += v;
}

// ---- block5: g = lrelu((X . W5^T)*s5+b5), atomic max over n into gfeat -------------------
// R20: thread owns 2 output float4 slots (og, og+128) x 8 rows; 4 row-groups over 512 thr.
// Per c4 iter/thread: 8 ds_read_b128 : 256 FMA (1:32) — R19's 1:16 was LDS-pipe bound.
// acc[8][2][4]=64 + 8 w-float4=32 => ~115 VGPR (<=128 keeps 16 waves/CU; no min-waves bound
// per R2 lesson). Distinct W5T per c4 iter = 16KB -> L1-resident despite 4x in-block reuse.
constexpr int RB = 32;
__global__ __launch_bounds__(512) void k_stage5(const float* __restrict__ X,
                                                const float* __restrict__ W5T,
                                                const float* __restrict__ s5,
                                                const float* __restrict__ b5,
                                                float* __restrict__ gfeat) {
    int blk = blockIdx.x;
    int b = blk / (NN / RB);
    int n0 = (blk % (NN / RB)) * RB;
    __shared__ float4 rows4[RB][X4S];     // 41472 B
    int tid = threadIdx.x;
    const float4* X4 = (const float4*)X;
    for (int j = tid; j < RB * X4S; j += 512) {
        int r = j / X4S, c = j - r * X4S;
        rows4[r][c] = X4[(size_t)(b * NN + n0 + r) * X4S + c];
    }
    __syncthreads();
    const float4* W5T4 = (const float4*)W5T;   // [XS][256] float4 per row
    int og = tid & 127;                   // slot pair: og (outputs og*4..) and og+128
    int r0 = (tid >> 7) * 8;              // 4 row-groups x 8 rows (wave-uniform)
    float acc[8][2][4] = {};
    for (int c4 = 0; c4 < X4S; ++c4) {
        float4 wA0 = W5T4[(size_t)(4 * c4 + 0) * 256 + og];
        float4 wA1 = W5T4[(size_t)(4 * c4 + 1) * 256 + og];
        float4 wA2 = W5T4[(size_t)(4 * c4 + 2) * 256 + og];
        float4 wA3 = W5T4[(size_t)(4 * c4 + 3) * 256 + og];
        float4 wB0 = W5T4[(size_t)(4 * c4 + 0) * 256 + og + 128];
        float4 wB1 = W5T4[(size_t)(4 * c4 + 1) * 256 + og + 128];
        float4 wB2 = W5T4[(size_t)(4 * c4 + 2) * 256 + og + 128];
        float4 wB3 = W5T4[(size_t)(4 * c4 + 3) * 256 + og + 128];
#pragma unroll
        for (int r = 0; r < 8; ++r) {
            float4 a = rows4[r0 + r][c4];
            acc[r][0][0] = fmaf(a.x, wA0.x, acc[r][0][0]);
            acc[r][0][1] = fmaf(a.x, wA0.y, acc[r][0][1]);
            acc[r][0][2] = fmaf(a.x, wA0.z, acc[r][0][2]);
            acc[r][0][3] = fmaf(a.x, wA0.w, acc[r][0][3]);
            acc[r][0][0] = fmaf(a.y, wA1.x, acc[r][0][0]);
            acc[r][0][1] = fmaf(a.y, wA1.y, acc[r][0][1]);
            acc[r][0][2] = fmaf(a.y, wA1.z, acc[r][0][2]);
            acc[r][0][3] = fmaf(a.y, wA1.w, acc[r][0][3]);
            acc[r][0][0] = fmaf(a.z, wA2.x, acc[r][0][0]);
            acc[r][0][1] = fmaf(a.z, wA2.y, acc[r][0][1]);
            acc[r][0][2] = fmaf(a.z, wA2.z, acc[r][0][2]);
            acc[r][0][3] = fmaf(a.z, wA2.w, acc[r][0][3]);
            acc[r][0][0] = fmaf(a.w, wA3.x, acc[r][0][0]);
            acc[r][0][1] = fmaf(a.w, wA3.y, acc[r][0][1]);
            acc[r][0][2] = fmaf(a.w, wA3.z, acc[r][0][2]);
            acc[r][0][3] = fmaf(a.w, wA3.w, acc[r][0][3]);
            acc[r][1][0] = fmaf(a.x, wB0.x, acc[r][1][0]);
            acc[r][1][1] = fmaf(a.x, wB0.y, acc[r][1][1]);
            acc[r][1][2] = fmaf(a.x, wB0.z, acc[r][1][2]);
            acc[r][1][3] = fmaf(a.x, wB0.w, acc[r][1][3]);
            acc[r][1][0] = fmaf(a.y, wB1.x, acc[r][1][0]);
            acc[r][1][1] = fmaf(a.y, wB1.y, acc[r][1][1]);
            acc[r][1][2] = fmaf(a.y, wB1.z, acc[r][1][2]);
            acc[r][1][3] = fmaf(a.y, wB1.w, acc[r][1][3]);
            acc[r][1][0] = fmaf(a.z, wB2.x, acc[r][1][0]);
            acc[r][1][1] = fmaf(a.z, wB2.y, acc[r][1][1]);
            acc[r][1][2] = fmaf(a.z, wB2.z, acc[r][1][2]);
            acc[r][1][3] = fmaf(a.z, wB2.w, acc[r][1][3]);
            acc[r][1][0] = fmaf(a.w, wB3.x, acc[r][1][0]);
            acc[r][1][1] = fmaf(a.w, wB3.y, acc[r][1][1]);
            acc[r][1][2] = fmaf(a.w, wB3.z, acc[r][1][2]);
            acc[r][1][3] = fmaf(a.w, wB3.w, acc[r][1][3]);
        }
    }
#pragma unroll
    for (int s = 0; s < 2; ++s) {
        int o0 = (og + 128 * s) * 4;
#pragma unroll
        for (int i = 0; i < 4; ++i) {
            int o = o0 + i;
            float sc = s5[o], bbv = b5[o];
            float mx = -INFINITY;
#pragma unroll
            for (int r = 0; r < 8; ++r) {
                float v = lrelu(acc[r][s][i] * sc + bbv);
                mx = fmaxf(v, mx);
            }
            atomicMaxF(&gfeat[b * 1024 + o], mx);
        }
    }
}

// ---- fused FC head: fc1 -> fc2 -> fc3 per batch row, intermediates in LDS ----------------
__global__ __launch_bounds__(256) void k_fc(const float* __restrict__ gfeat,
                                            const float* __restrict__ fW1, const float* __restrict__ fb1,
                                            const float* __restrict__ fs1, const float* __restrict__ fB1,
                                            const float* __restrict__ fW2, const float* __restrict__ fb2,
                                            const float* __restrict__ fs2, const float* __restrict__ fB2,
                                            const float* __restrict__ fW3, const float* __restrict__ fb3,
                                            float* __restrict__ logits) {
    int b = blockIdx.x;
    __shared__ float g[1024];
    __shared__ float h1s[512];
    __shared__ float h2s[256];
    int tid = threadIdx.x;
    for (int j = tid; j < 1024; j += 256) g[j] = gfeat[b * 1024 + j];
    __syncthreads();
    for (int o = tid; o < 512; o += 256) {
        const float* wr = fW1 + (size_t)o * 1024;
        float acc = 0.f;
        for (int c = 0; c < 1024; ++c) acc = fmaf(g[c], wr[c], acc);
        h1s[o] = lrelu((acc + fb1[o]) * fs1[o] + fB1[o]);
    }
    __syncthreads();
    {
        int o = tid;
        const float* wr = fW2 + (size_t)o * 512;
        float acc = 0.f;
        for (int c = 0; c < 512; ++c) acc = fmaf(h1s[c], wr[c], acc);
        h2s[o] = lrelu((acc + fb2[o]) * fs2[o] + fB2[o]);
    }
    __syncthreads();
    if (tid < 40) {
        const float* wr = fW3 + (size_t)tid * 256;
        float acc = 0.f;
        for (int c = 0; c < 256; ++c) acc = fmaf(h2s[c], wr[c], acc);
        logits[b * 40 + tid] = acc + fb3[tid];
    }
}

extern "C" void kernel_launch(void* const* d_in, const int* in_sizes, int n_in,
                              void* d_out, int out_size, void* d_ws, size_t ws_size,
                              hipStream_t stream) {
    const float* x   = (const float*)d_in[0];
    const float* W1  = (const float*)d_in[1];
    const float* s1  = (const float*)d_in[2];
    const float* b1  = (const float*)d_in[3];
    const float* W2  = (const float*)d_in[4];
    const float* s2  = (const float*)d_in[5];
    const float* b2  = (const float*)d_in[6];
    const float* W3  = (const float*)d_in[7];
    const float* s3  = (const float*)d_in[8];
    const float* b3  = (const float*)d_in[9];
    const float* W4  = (const float*)d_in[10];
    const float* s4  = (const float*)d_in[11];
    const float* b4  = (const float*)d_in[12];
    const float* W5  = (const float*)d_in[13];
    const float* s5  = (const float*)d_in[14];
    const float* b5  = (const float*)d_in[15];
    const float* fW1 = (const float*)d_in[16];
    const float* fb1 = (const float*)d_in[17];
    const float* fs1 = (const float*)d_in[18];
    const float* fB1 = (const float*)d_in[19];
    const float* fW2 = (const float*)d_in[20];
    const float* fb2 = (const float*)d_in[21];
    const float* fs2 = (const float*)d_in[22];
    const float* fB2 = (const float*)d_in[23];
    const float* fW3 = (const float*)d_in[24];
    const float* fb3 = (const float*)d_in[25];

    float* out    = (float*)d_out;
    float* logits = out;          // 8*40
    float* gfeat  = out + 320;    // 8*1024

    char* ws = (char*)d_ws;
    size_t off = 0;
    auto alloc = [&](size_t bytes) -> void* {
        void* p = ws + off;
        off += (bytes + 255) & ~(size_t)255;
        return p;
    };
    float* X    = (float*)alloc((size_t)BB * NN * XS * 4);      // 21.2 MB
    float* sq   = (float*)alloc((size_t)BB * NN * 4);
    float* dist = (float*)alloc((size_t)BB * NN * NN * 4);      // 134 MB
    int*   idx  = (int*)  alloc((size_t)BB * NN * KK * 4);
    float4* WT4 = (float4*)alloc((size_t)WTOT * 16);            // 305 KB
    float* H    = (float*)alloc((size_t)BB * NN * 128 * 4);     // 8.4 MB
    float* G    = (float*)alloc((size_t)BB * NN * 128 * 4);     // 8.4 MB
    float* W5T  = (float*)alloc((size_t)XS * 1024 * 4);
    (void)ws_size; (void)in_sizes; (void)n_in; (void)out_size;

    // one-shot prep: WT packs + W5T + gfeat init + transpose/sq0 + X zero-fill
    int prepTot = WTOT + XS * 1024 + BB * 1024 + BB * NN + BB * NN * 80;
    k_prep_all<<<(prepTot + 255) / 256, 256, 0, stream>>>(W1, W2, W3, W4, W5, x,
                                                          WT4, W5T, gfeat, X, sq);

    const int Cs[4]    = {3, 67, 131, 195};
    const int offs[4]  = {3, 67, 131, 195};
    const int WOFF[4]  = {0, 128, 2304, 6528};  // channel-row base in packed WT4
    const float* ss[4] = {s1, s2, s3, s4};
    const float* bs[4] = {b1, b2, b3, b4};

    constexpr int NT = NN / TM;                 // 16 tiles per dim
    constexpr int NBLK = NT * (NT + 1) / 2;     // 136 lower-triangle tiles
    for (int st = 0; st < 4; ++st) {
        int C = Cs[st];
        dim3 dg(NBLK, 1, BB);
        k_dist<<<dg, 256, 0, stream>>>(X, sq, dist, C);
        k_select<<<BB * NN, 128, 0, stream>>>(dist, idx);
        const float4* wt = WT4 + WOFF[st];
        switch (st) {
            case 0:
                k_hg<1, 64><<<BB * NN / 32, 256, 0, stream>>>(X, wt, H, G);
                k_edgemax<64><<<BB * NN / 4, 256, 0, stream>>>(H, G, idx, ss[st], bs[st], offs[st], X, sq);
                break;
            case 1:
                k_hg<17, 64><<<BB * NN / 32, 256, 0, stream>>>(X, wt, H, G);
                k_edgemax<64><<<BB * NN / 4, 256, 0, stream>>>(H, G, idx, ss[st], bs[st], offs[st], X, sq);
                break;
            case 2:
                k_hg<33, 64><<<BB * NN / 32, 256, 0, stream>>>(X, wt, H, G);
                k_edgemax<64><<<BB * NN / 4, 256, 0, stream>>>(H, G, idx, ss[st], bs[st], offs[st], X, sq);
                break;
            case 3:
                k_hg<49, 128><<<BB * NN / 32, 256, 0, stream>>>(X, wt, H, G);
                k_edgemax<128><<<BB * NN / 4, 256, 0, stream>>>(H, G, idx, ss[st], bs[st], offs[st], X, sq);
                break;
        }
    }

    k_stage5<<<BB * (NN / RB), 512, 0, stream>>>(X, W5T, s5, b5, gfeat);
    k_fc<<<BB, 256, 0, stream>>>(gfeat, fW1, fb1, fs1, fB1,
                                 fW2, fb2, fs2, fB2, fW3, fb3, logits);
}